// Round 6
// baseline (436.287 us; speedup 1.0000x reference)
//
#include <hip/hip_runtime.h>
#include <hip/hip_bf16.h>
#include <cstdint>

namespace {

constexpr int B = 4, N = 300, D = 256;
constexpr int G = 4, PIN = 32, POUT = 128;
constexpr int CG = D / G;                    // 64
constexpr int TOTAL = CG * CG + PIN * POUT;  // 8192
constexpr int BN_TOT = B * N;                // 1200
constexpr int BN_PAD = 1216;                 // 19 * 64
constexpr int GT = G * TOTAL;                // 32768

typedef short s16x8 __attribute__((ext_vector_type(8)));   // 8 bf16 = 4 VGPRs
typedef float f32x4 __attribute__((ext_vector_type(4)));

// ---- bf16 helpers (bit-level, RNE) ----
__device__ __forceinline__ float bf2f(unsigned short u) {
  union { unsigned int i; float f; } x; x.i = ((unsigned int)u) << 16; return x.f;
}
__device__ __forceinline__ unsigned short f2bf(float f) {
  union { float f; unsigned int i; } x; x.f = f;
  unsigned int r = x.i + 0x7fffu + ((x.i >> 16) & 1u);
  return (unsigned short)(r >> 16);
}

// async global->LDS, 16 B per lane, dest = lds_base + lane*16
__device__ __forceinline__ void gld_lds16(const void* g, void* l) {
  __builtin_amdgcn_global_load_lds(
      (const __attribute__((address_space(1))) unsigned int*)g,
      (__attribute__((address_space(3))) unsigned int*)l, 16, 0, 0);
}

__device__ __forceinline__ void breduce2(float& a, float& b, volatile float* red) {
  __syncthreads();
  #pragma unroll
  for (int off = 32; off; off >>= 1) {
    a += __shfl_down(a, off, 64);
    b += __shfl_down(b, off, 64);
  }
  int t = threadIdx.x;
  if ((t & 63) == 0) { red[t >> 6] = a; red[4 + (t >> 6)] = b; }
  __syncthreads();
  a = red[0] + red[1] + red[2] + red[3];
  b = red[4] + red[5] + red[6] + red[7];
}

// ---------------- prep: fp32 [R][C] -> bf16 transposed [C][R] ---------------
// mperm=1: within each 8192-column group, the first 4096 output rows get the
// involution local' = (local&63)<<6 | local>>6 — so pgemm emits M transposed.
__global__ __launch_bounds__(256) void k_transpose(
    const float* __restrict__ in, unsigned short* __restrict__ out, int R, int C,
    int mperm) {
  __shared__ unsigned short T[64][72];
  int c0 = blockIdx.x * 64;
  int r0 = blockIdx.y * 64;
  int t = threadIdx.x;
  #pragma unroll
  for (int i = 0; i < 4; ++i) {
    int u = t + i * 256;
    int rr = u >> 4, c4 = (u & 15) * 4;
    float4 v = *(const float4*)(in + (size_t)(r0 + rr) * C + c0 + c4);
    ushort4 w;
    w.x = f2bf(v.x); w.y = f2bf(v.y); w.z = f2bf(v.z); w.w = f2bf(v.w);
    *(ushort4*)&T[rr][c4] = w;
  }
  __syncthreads();
  #pragma unroll
  for (int i = 0; i < 2; ++i) {
    int u = t + i * 256;
    int c = u >> 3, rr8 = (u & 7) * 8;
    unsigned short tmp[8];
    #pragma unroll
    for (int j = 0; j < 8; ++j) tmp[j] = T[rr8 + j][c];
    int n = c0 + c;
    if (mperm) {
      int local = n & 8191;
      if (local < 4096) n = (n & ~8191) | ((local & 63) << 6) | (local >> 6);
    }
    *(uint4*)(out + (size_t)n * R + r0 + rr8) = *(const uint4*)tmp;
  }
}

// ------------- prep: feat fp32 [B][256][HW] -> bf16 [B][HW][256] ------------
__global__ __launch_bounds__(256) void k_featT(
    const float* __restrict__ in, unsigned short* __restrict__ out, int HW) {
  __shared__ unsigned short T[64][72];
  int hw0 = blockIdx.x * 64;
  int d0 = blockIdx.y * 64;
  int bb = blockIdx.z;
  int t = threadIdx.x;
  #pragma unroll
  for (int i = 0; i < 4; ++i) {
    int u = t + i * 256;
    int rr = u >> 4, c4 = (u & 15) * 4;   // rr = channel-in-tile, c4 = pixel
    if (hw0 + c4 + 3 < HW) {
      float4 v = *(const float4*)(in + ((size_t)(bb * D + d0 + rr)) * HW + hw0 + c4);
      ushort4 w;
      w.x = f2bf(v.x); w.y = f2bf(v.y); w.z = f2bf(v.z); w.w = f2bf(v.w);
      *(ushort4*)&T[rr][c4] = w;
    }
  }
  __syncthreads();
  #pragma unroll
  for (int i = 0; i < 2; ++i) {
    int u = t + i * 256;
    int p = u >> 3, dd8 = (u & 7) * 8;    // p = pixel-in-tile, dd8 = channel
    if (hw0 + p < HW) {
      unsigned short tmp[8];
      #pragma unroll
      for (int j = 0; j < 8; ++j) tmp[j] = T[dd8 + j][p];
      *(uint4*)(out + ((size_t)(bb * HW + hw0 + p)) * D + d0 + dd8) = *(const uint4*)tmp;
    }
  }
}

// ---------------- prep: qf fp32 [1200][256] -> bf16 [1216][256] -------------
__global__ __launch_bounds__(256) void k_cvt_qf(
    const float* __restrict__ qf, unsigned short* __restrict__ qb) {
  int e = (blockIdx.x * 256 + threadIdx.x) * 4;
  int row = e >> 8;
  ushort4 w;
  if (row < BN_TOT) {
    float4 v = *(const float4*)(qf + e);
    w.x = f2bf(v.x); w.y = f2bf(v.y); w.z = f2bf(v.z); w.w = f2bf(v.w);
  } else {
    w.x = w.y = w.z = w.w = 0;
  }
  *(ushort4*)(qb + e) = w;
}

// ---------------- kernel 0: offset GEMM (fp32) ------------------------------
__global__ __launch_bounds__(384) void k_off(
    const float* __restrict__ qf, const float* __restrict__ offw,
    const float* __restrict__ offb, float* __restrict__ offsets) {
  int r0 = blockIdx.x * 16;
  int t = threadIdx.x;
  __shared__ float Q[16][256];
  for (int i = t; i < 16 * 256; i += 384)
    Q[i >> 8][i & 255] = qf[(size_t)(r0 + (i >> 8)) * 256 + (i & 255)];
  __syncthreads();
  float acc[16];
  float bias = offb[t];
  #pragma unroll
  for (int r = 0; r < 16; ++r) acc[r] = bias;
  for (int d = 0; d < 256; ++d) {
    float w = offw[(size_t)d * 384 + t];
    #pragma unroll
    for (int r = 0; r < 16; ++r) acc[r] += Q[r][d] * w;
  }
  #pragma unroll
  for (int r = 0; r < 16; ++r) offsets[(size_t)(r0 + r) * 384 + t] = acc[r];
}

// ---------------- kernel 1: bilinear gather, branch-free + deep MLP ---------
__global__ __launch_bounds__(256) void k_gather(
    const float* __restrict__ roi, const float* __restrict__ offsets,
    const unsigned short* __restrict__ featT, unsigned short* __restrict__ sampled) {
  int bn = blockIdx.x;
  int bb = bn / N;
  int t = threadIdx.x;
  __shared__ int   widx[2048];   // [j][l][corner] element offset into featT
  __shared__ float wval[2048];

  const int Wl[4] = {160, 80, 40, 20};
  const int Hl[4] = {100, 50, 25, 13};
  const int loff[4] = {0, 16384000, 20480000, 21504000};
  const int HWl[4] = {16000, 4000, 1000, 260};
  const float sl[4] = {8.f, 16.f, 32.f, 64.f};

  float cx = roi[bn * 4 + 0], cy = roi[bn * 4 + 1];
  float z = roi[bn * 4 + 2], r = roi[bn * 4 + 3];
  float scale = exp2f(z);
  float rwx = scale * exp2f(-0.5f * r);
  float rhy = scale * exp2f(0.5f * r);

  #pragma unroll
  for (int task = t; task < 512; task += 256) {   // task = j*4 + l
    int j = task >> 2, l = task & 3;
    float ox = offsets[(size_t)bn * 384 + j * 3 + 0];
    float oy = offsets[(size_t)bn * 384 + j * 3 + 1];
    float oz = offsets[(size_t)bn * 384 + j * 3 + 2];
    float sx = cx + ox * rwx;
    float sy = cy + oy * rhy;
    float sz = z + oz;
    float lw[4];
    float m = -1e30f;
    #pragma unroll
    for (int ll = 0; ll < 4; ++ll) {
      float dlt = sz - 3.0f - (float)ll;
      lw[ll] = -dlt * dlt * 0.5f;
      m = fmaxf(m, lw[ll]);
    }
    float s = 0.f;
    #pragma unroll
    for (int ll = 0; ll < 4; ++ll) { lw[ll] = expf(lw[ll] - m); s += lw[ll]; }
    float wl_ = lw[l] / s;

    int W = Wl[l], H = Hl[l];
    float px = sx / sl[l] - 0.5f;
    float py = sy / sl[l] - 0.5f;
    float x0f = floorf(px), y0f = floorf(py);
    int x0 = (int)x0f, y0 = (int)y0f;
    float fx = px - x0f, fy = py - y0f;
    int base = loff[l] + bb * HWl[l] * 256;
    #pragma unroll
    for (int k = 0; k < 4; ++k) {
      int xi = x0 + (k & 1), yi = y0 + (k >> 1);
      bool valid = (xi >= 0) & (xi < W) & (yi >= 0) & (yi < H);
      int xc = min(max(xi, 0), W - 1), yc = min(max(yi, 0), H - 1);
      float wgt = ((k & 1) ? fx : 1.f - fx) * ((k >> 1) ? fy : 1.f - fy) * wl_;
      widx[j * 16 + l * 4 + k] = base + (yc * W + xc) * 256;
      wval[j * 16 + l * 4 + k] = valid ? wgt : 0.f;
    }
  }
  __syncthreads();

  int wave = t >> 6, lane = t & 63;
  int half = lane >> 5, ln = lane & 31;
  const unsigned short* fb = featT + wave * 64 + ln * 2;
  #pragma unroll 2
  for (int it = 0; it < 16; ++it) {
    int p = it * 2 + half;
    int j = wave * 32 + p;
    int ix[16]; float w[16]; unsigned int u[16];
    #pragma unroll
    for (int k = 0; k < 16; ++k) { ix[k] = widx[j * 16 + k]; w[k] = wval[j * 16 + k]; }
    #pragma unroll
    for (int k = 0; k < 16; ++k) u[k] = *(const unsigned int*)(fb + ix[k]);
    float a0 = 0.f, a1 = 0.f;
    #pragma unroll
    for (int k = 0; k < 16; ++k) {
      a0 += w[k] * bf2f((unsigned short)(u[k] & 0xffffu));
      a1 += w[k] * bf2f((unsigned short)(u[k] >> 16));
    }
    unsigned int packed = (unsigned int)f2bf(a0) | ((unsigned int)f2bf(a1) << 16);
    *(unsigned int*)(sampled + (((size_t)bn * G + wave) * PIN + p) * CG + ln * 2) = packed;
  }
}

// ---------------- kernel 2: params GEMM via MFMA + global_load_lds ----------
// 64 rows x 256 cols per block; XOR-swizzled LDS (stride 64, c16' = c16^(row&7))
__global__ __launch_bounds__(256) void k_pgemm(
    const unsigned short* __restrict__ A, const unsigned short* __restrict__ Bt,
    const float* __restrict__ pgb, unsigned short* __restrict__ params) {
  __shared__ __attribute__((aligned(16))) unsigned short As[64 * 64];    //  8 KB
  __shared__ __attribute__((aligned(16))) unsigned short Bs[256 * 64];   // 32 KB
  int col0 = blockIdx.x * 256;
  int row0 = blockIdx.y * 64;
  int t = threadIdx.x;
  int w = t >> 6, lane = t & 63, lr = lane & 15, q = lane >> 4;
  int srow = lane >> 3;                 // staging: row-within-8
  int sc16 = (lane & 7) ^ srow;         // staging: unswizzled 16B-unit
  f32x4 acc[4][4] = {};
  for (int k0 = 0; k0 < D; k0 += 64) {
    #pragma unroll
    for (int i = 0; i < 2; ++i) {       // A: 8 wave-issues total
      int n = (w * 2 + i) * 8 + srow;
      gld_lds16(A + (size_t)(row0 + n) * D + k0 + sc16 * 8, As + (w * 2 + i) * 512);
    }
    #pragma unroll
    for (int i = 0; i < 8; ++i) {       // B: 32 wave-issues total
      int n = (w * 8 + i) * 8 + srow;
      gld_lds16(Bt + (size_t)(col0 + n) * D + k0 + sc16 * 8, Bs + (w * 8 + i) * 512);
    }
    __syncthreads();
    #pragma unroll
    for (int ks = 0; ks < 2; ++ks) {
      int c16 = ks * 4 + q;
      s16x8 af[4], bf[4];
      #pragma unroll
      for (int mi = 0; mi < 4; ++mi) {
        int rrow = mi * 16 + lr;
        af[mi] = *(const s16x8*)(As + rrow * 64 + ((c16 ^ (rrow & 7)) * 8));
      }
      #pragma unroll
      for (int ni = 0; ni < 4; ++ni) {
        int brow = w * 64 + ni * 16 + lr;
        bf[ni] = *(const s16x8*)(Bs + brow * 64 + ((c16 ^ (brow & 7)) * 8));
      }
      #pragma unroll
      for (int mi = 0; mi < 4; ++mi)
        #pragma unroll
        for (int ni = 0; ni < 4; ++ni)
          acc[mi][ni] = __builtin_amdgcn_mfma_f32_16x16x32_bf16(af[mi], bf[ni], acc[mi][ni], 0, 0, 0);
    }
    __syncthreads();
  }
  #pragma unroll
  for (int ni = 0; ni < 4; ++ni) {
    int c = col0 + w * 64 + ni * 16 + lr;
    // column c holds original column perm(c) (M-region involution) -> its bias
    int local = c & 8191;
    int cb = (local < 4096) ? ((c & ~8191) | ((local & 63) << 6) | (local >> 6)) : c;
    float bias = pgb[cb];
    #pragma unroll
    for (int mi = 0; mi < 4; ++mi) {
      #pragma unroll
      for (int rg = 0; rg < 4; ++rg) {
        int rr = row0 + mi * 16 + q * 4 + rg;
        if (rr < BN_TOT) params[(size_t)rr * GT + c] = f2bf(acc[mi][ni][rg] + bias);
      }
    }
  }
}

// ---------------- kernel 3: per-(b,n,g) mixing via MFMA ---------------------
__global__ __launch_bounds__(256) void k_mixing(
    const unsigned short* __restrict__ sampled,
    const unsigned short* __restrict__ params,
    unsigned short* __restrict__ h2out) {
  int blk = blockIdx.x;
  int g = blk & 3, bn = blk >> 2;
  const unsigned short* P = params + (size_t)bn * GT + (size_t)g * TOTAL;
  const unsigned short* Sp = sampled + (((size_t)bn * G + g) * PIN) * CG;
  __shared__ unsigned short Ht[64][40];   // h1^T, rows 80 B (16B-aligned)
  __shared__ float red[8];
  int t = threadIdx.x;
  int w = t >> 6, lane = t & 63, lr = lane & 15, q = lane >> 4;

  // ---- h1 = sampled(32x64) @ M(64x64) ----
  f32x4 acc1[2] = {};
  #pragma unroll
  for (int ks = 0; ks < 2; ++ks) {
    s16x8 b = *(const s16x8*)(P + (w * 16 + lr) * 64 + ks * 32 + q * 8);  // Mt[d][c]
    #pragma unroll
    for (int mt = 0; mt < 2; ++mt) {
      s16x8 a = *(const s16x8*)(Sp + (mt * 16 + lr) * 64 + ks * 32 + q * 8);
      acc1[mt] = __builtin_amdgcn_mfma_f32_16x16x32_bf16(a, b, acc1[mt], 0, 0, 0);
    }
  }
  float s1 = 0.f, ss1 = 0.f;
  #pragma unroll
  for (int mt = 0; mt < 2; ++mt)
    #pragma unroll
    for (int rg = 0; rg < 4; ++rg) { float v = acc1[mt][rg]; s1 += v; ss1 += v * v; }
  breduce2(s1, ss1, red);
  {
    float mu = s1 * (1.f / 2048.f);
    float var = ss1 * (1.f / 2048.f) - mu * mu;
    float rs = rsqrtf(var + 1e-5f);
    #pragma unroll
    for (int mt = 0; mt < 2; ++mt) {
      unsigned short pk[4];
      #pragma unroll
      for (int rg = 0; rg < 4; ++rg) {
        float v = (acc1[mt][rg] - mu) * rs;
        pk[rg] = f2bf(v > 0.f ? v : 0.f);
      }
      *(uint2*)&Ht[w * 16 + lr][mt * 16 + q * 4] = *(const uint2*)pk;
    }
  }
  __syncthreads();

  // ---- h2 = S(128x32) @ h1(32x64) ----
  f32x4 acc2[2][4] = {};
  #pragma unroll
  for (int mt = 0; mt < 2; ++mt) {
    int o = w * 32 + mt * 16 + lr;
    s16x8 a = *(const s16x8*)(P + 4096 + o * 32 + q * 8);   // S[o][p]
    #pragma unroll
    for (int nt = 0; nt < 4; ++nt) {
      s16x8 b = *(const s16x8*)&Ht[nt * 16 + lr][q * 8];    // h1^T[d][p]
      acc2[mt][nt] = __builtin_amdgcn_mfma_f32_16x16x32_bf16(a, b, acc2[mt][nt], 0, 0, 0);
    }
  }
  float s2 = 0.f, ss2 = 0.f;
  #pragma unroll
  for (int mt = 0; mt < 2; ++mt)
    #pragma unroll
    for (int nt = 0; nt < 4; ++nt)
      #pragma unroll
      for (int rg = 0; rg < 4; ++rg) { float v = acc2[mt][nt][rg]; s2 += v; ss2 += v * v; }
  breduce2(s2, ss2, red);
  {
    float mu = s2 * (1.f / 8192.f);
    float var = ss2 * (1.f / 8192.f) - mu * mu;
    float rs = rsqrtf(var + 1e-5f);
    unsigned short* dst = h2out + (size_t)bn * GT + (size_t)g * TOTAL;
    #pragma unroll
    for (int mt = 0; mt < 2; ++mt) {
      #pragma unroll
      for (int nt = 0; nt < 4; ++nt) {
        int d = nt * 16 + lr;
        #pragma unroll
        for (int rg = 0; rg < 4; ++rg) {
          int o = w * 32 + mt * 16 + q * 4 + rg;
          float v = (acc2[mt][nt][rg] - mu) * rs;
          dst[o * 64 + d] = f2bf(v > 0.f ? v : 0.f);
        }
      }
    }
  }
}

// ---------------- kernel 4: output GEMM via MFMA + global_load_lds ----------
constexpr int KSPLIT = 32, KCH = GT / KSPLIT;  // 1024
__global__ __launch_bounds__(256) void k_ogemm(
    const unsigned short* __restrict__ A, const unsigned short* __restrict__ Bt,
    float* __restrict__ parts) {
  __shared__ __attribute__((aligned(16))) unsigned short As[64 * 64];    //  8 KB
  __shared__ __attribute__((aligned(16))) unsigned short Bs[256 * 64];   // 32 KB
  int row0 = blockIdx.x * 64;
  int z = blockIdx.y;
  int kbase = z * KCH;
  int t = threadIdx.x;
  int w = t >> 6, lane = t & 63, lr = lane & 15, q = lane >> 4;
  int srow = lane >> 3;
  int sc16 = (lane & 7) ^ srow;
  f32x4 acc[4][4] = {};
  for (int k0 = 0; k0 < KCH; k0 += 64) {
    #pragma unroll
    for (int i = 0; i < 2; ++i) {
      int n = (w * 2 + i) * 8 + srow;
      gld_lds16(A + (size_t)(row0 + n) * GT + kbase + k0 + sc16 * 8, As + (w * 2 + i) * 512);
    }
    #pragma unroll
    for (int i = 0; i < 8; ++i) {
      int n = (w * 8 + i) * 8 + srow;
      gld_lds16(Bt + (size_t)n * GT + kbase + k0 + sc16 * 8, Bs + (w * 8 + i) * 512);
    }
    __syncthreads();
    #pragma unroll
    for (int ks = 0; ks < 2; ++ks) {
      int c16 = ks * 4 + q;
      s16x8 af[4], bf[4];
      #pragma unroll
      for (int mi = 0; mi < 4; ++mi) {
        int rrow = mi * 16 + lr;
        af[mi] = *(const s16x8*)(As + rrow * 64 + ((c16 ^ (rrow & 7)) * 8));
      }
      #pragma unroll
      for (int ni = 0; ni < 4; ++ni) {
        int brow = w * 64 + ni * 16 + lr;
        bf[ni] = *(const s16x8*)(Bs + brow * 64 + ((c16 ^ (brow & 7)) * 8));
      }
      #pragma unroll
      for (int mi = 0; mi < 4; ++mi)
        #pragma unroll
        for (int ni = 0; ni < 4; ++ni)
          acc[mi][ni] = __builtin_amdgcn_mfma_f32_16x16x32_bf16(af[mi], bf[ni], acc[mi][ni], 0, 0, 0);
    }
    __syncthreads();
  }
  #pragma unroll
  for (int mi = 0; mi < 4; ++mi) {
    #pragma unroll
    for (int ni = 0; ni < 4; ++ni) {
      int c = w * 64 + ni * 16 + lr;
      #pragma unroll
      for (int rg = 0; rg < 4; ++rg) {
        int rr = row0 + mi * 16 + q * 4 + rg;
        if (rr < BN_TOT)
          parts[((size_t)z * BN_PAD + rr) * D + c] = acc[mi][ni][rg];
      }
    }
  }
}

// ---------------- kernel 5: K-split reduce + residual + LN1 ------------------
__global__ __launch_bounds__(256) void k_final(
    const float* __restrict__ qf, const float* __restrict__ opb,
    const float* __restrict__ parts, const float* __restrict__ lng,
    const float* __restrict__ lnb, float* __restrict__ out) {
  int bn = blockIdx.x;
  int d = threadIdx.x;
  float v = qf[(size_t)bn * D + d] + opb[d];
  #pragma unroll
  for (int s = 0; s < KSPLIT; ++s) v += parts[((size_t)s * BN_PAD + bn) * D + d];
  __shared__ float red[8];
  float a = v, b2 = v * v;
  breduce2(a, b2, red);
  float mu = a * (1.f / D);
  float var = b2 * (1.f / D) - mu * mu;
  float rs = rsqrtf(var + 1e-5f);
  out[(size_t)bn * D + d] = (v - mu) * rs * lng[d] + lnb[d];
}

}  // namespace

extern "C" void kernel_launch(void* const* d_in, const int* in_sizes, int n_in,
                              void* d_out, int out_size, void* d_ws, size_t ws_size,
                              hipStream_t stream) {
  const float* f0 = (const float*)d_in[0];
  const float* f1 = (const float*)d_in[1];
  const float* f2 = (const float*)d_in[2];
  const float* f3 = (const float*)d_in[3];
  const float* qf = (const float*)d_in[4];
  const float* roi = (const float*)d_in[5];
  const float* off_w = (const float*)d_in[6];
  const float* off_b = (const float*)d_in[7];
  const float* pg_w = (const float*)d_in[8];
  const float* pg_b = (const float*)d_in[9];
  const float* op_w = (const float*)d_in[10];
  const float* op_b = (const float*)d_in[11];
  const float* ln_g = (const float*)d_in[12];
  const float* ln_b = (const float*)d_in[13];
  float* out = (float*)d_out;

  // workspace layout (bytes):
  //   sampled bf16 : 19,660,800
  //   h2      bf16 : 79,691,776   (featT bf16 43,540,480 aliases this slot)
  //   params  bf16 : 79,691,776   (parts fp32 39,845,888 aliases after mixing)
  //   wT      bf16 : 16,777,216   (pg_wT, then op_wT)
  //   qf_bf16      :    622,592
  //   offsets fp32 :  1,843,200
  //   total ~ 198.3 MB
  char* ws = (char*)d_ws;
  unsigned short* sampled = (unsigned short*)ws;
  unsigned short* h2      = (unsigned short*)(ws + 19660800ULL);
  unsigned short* featT   = h2;  // alias
  unsigned short* params  = (unsigned short*)(ws + 19660800ULL + 79691776ULL);
  float*          parts   = (float*)(ws + 19660800ULL + 79691776ULL);  // alias
  unsigned short* wT      = (unsigned short*)(ws + 19660800ULL + 2 * 79691776ULL);
  unsigned short* qfb     = (unsigned short*)(ws + 19660800ULL + 2 * 79691776ULL + 16777216ULL);
  float*          offsets = (float*)(ws + 19660800ULL + 2 * 79691776ULL + 16777216ULL + 622592ULL);

  k_featT<<<dim3(250, 4, B), 256, 0, stream>>>(f0, featT + 0,        16000);
  k_featT<<<dim3( 63, 4, B), 256, 0, stream>>>(f1, featT + 16384000, 4000);
  k_featT<<<dim3( 16, 4, B), 256, 0, stream>>>(f2, featT + 20480000, 1000);
  k_featT<<<dim3(  5, 4, B), 256, 0, stream>>>(f3, featT + 21504000, 260);
  k_off<<<BN_TOT / 16, 384, 0, stream>>>(qf, off_w, off_b, offsets);
  // pg_wT with M-region row involution (so pgemm emits M transposed)
  k_transpose<<<dim3(GT / 64, D / 64), 256, 0, stream>>>(pg_w, wT, D, GT, 1);
  k_cvt_qf<<<BN_PAD * D / 1024, 256, 0, stream>>>(qf, qfb);
  k_gather<<<BN_TOT, 256, 0, stream>>>(roi, offsets, featT, sampled);
  k_pgemm<<<dim3(GT / 256, BN_PAD / 64), 256, 0, stream>>>(qfb, wT, pg_b, params);
  k_mixing<<<BN_TOT * G, 256, 0, stream>>>(sampled, params, h2);
  k_transpose<<<dim3(D / 64, GT / 64), 256, 0, stream>>>(op_w, wT, GT, D, 0);
  k_ogemm<<<dim3(BN_PAD / 64, KSPLIT), 256, 0, stream>>>(h2, wT, parts);
  k_final<<<BN_TOT, 256, 0, stream>>>(qf, op_b, parts, ln_g, ln_b, out);
}